// Round 7
// baseline (89.099 us; speedup 1.0000x reference)
//
#include <hip/hip_runtime.h>
#include <hip/hip_bf16.h>
#include <stdint.h>

#define HW 192
#define NC 128
#define KEPS 1e-5f
#define PTB 49152   /* full probe tile bytes */

typedef __attribute__((ext_vector_type(8))) short short8;
typedef __attribute__((ext_vector_type(4))) float f32x4;

__device__ __forceinline__ float max3f(float a, float b, float c) {
  float d;
  asm("v_max3_f32 %0, %1, %2, %3" : "=v"(d) : "v"(a), "v"(b), "v"(c));
  return d;
}

// ---------------------------------------------------------------------------
// Prep: f32 [n][C][HW] -> bf16 [n][HW][C] via LDS transpose (coalesced both
// sides). probT XOR-swizzled within each 256B row: byte col = (2c)^((hw&7)<<4).
// ---------------------------------------------------------------------------
__global__ __launch_bounds__(256)
void prep_kernel(const float* __restrict__ prob,
                 const float* __restrict__ gal,
                 unsigned short* __restrict__ probT,
                 unsigned short* __restrict__ galT) {
  __shared__ unsigned short lds[32 * 194];
  const int b = blockIdx.x;
  const int slice = b >> 2;
  const int cc = (b & 3) * 32;
  const bool isProbe = (slice < 64);
  const float* src = isProbe ? prob + (size_t)slice * NC * HW
                             : gal + (size_t)(slice - 64) * NC * HW;
  unsigned short* dst = isProbe ? probT + (size_t)slice * HW * NC
                                : galT + (size_t)(slice - 64) * HW * NC;
  const float* s0 = src + (size_t)cc * HW;
  #pragma unroll
  for (int k = 0; k < 24; ++k) {
    int i = k * 256 + threadIdx.x;
    int cp = i / HW;
    int hw = i - cp * HW;
    lds[cp * 194 + hw] =
        __builtin_bit_cast(unsigned short, __float2bfloat16(s0[i]));
  }
  __syncthreads();
  const int cp = threadIdx.x & 31;
  const int hw0 = threadIdx.x >> 5;
  const int c = cc + cp;
  #pragma unroll
  for (int k = 0; k < 24; ++k) {
    int hw = hw0 + 8 * k;
    unsigned short v = lds[cp * 194 + hw];
    int col = isProbe ? ((((2 * c) ^ ((hw & 7) << 4))) >> 1) : c;
    dst[hw * NC + col] = v;
  }
}

// ---------------------------------------------------------------------------
__device__ __forceinline__ void gl_lds16(const void* gsrc, void* ldst) {
  __builtin_amdgcn_global_load_lds(
      (const __attribute__((address_space(1))) void*)gsrc,
      (__attribute__((address_space(3))) void*)ldst, 16, 0, 0);
}

template <int CTRL>
__device__ __forceinline__ float dpp_max(float x) {
  int xi = __builtin_bit_cast(int, x);
  int yi = __builtin_amdgcn_update_dpp(xi, xi, CTRL, 0xf, 0xf, false);
  return fmaxf(x, __builtin_bit_cast(float, yi));
}
__device__ __forceinline__ float ror16_max(float x) {
  x = dpp_max<0x121>(x);
  x = dpp_max<0x122>(x);
  x = dpp_max<0x124>(x);
  x = dpp_max<0x128>(x);
  return x;
}

// ---------------------------------------------------------------------------
// Pair kernel: 512 blocks = g*8 + pc (8 probes each), 8 waves (512 thr),
// 1 block/CU. Wave (wr,wc) of 2x4: gal rows wr*96..+95 persistent in regs,
// probe cols wc*48..+47. Full 48KB probe tiles double-buffered via async
// global_load_lds; ONE barrier per probe; combine phase once at block end.
// Dynamic LDS: 2*49152 dbuf | cmP 8*2*192 | rmF 8*4*192 | redW 64 | red2 16.
// ---------------------------------------------------------------------------
extern __shared__ char smem[];

__global__ __launch_bounds__(512, 2)
void pair_kernel(const unsigned short* __restrict__ galT,
                 const unsigned short* __restrict__ probT,
                 const float* __restrict__ fc_w,
                 float* __restrict__ Wout,
                 float* __restrict__ sPart,
                 float* __restrict__ qPart) {
  char* dbuf = smem;                           // [2][49152]
  float* cmP = (float*)(smem + 98304);         // [pi][wr][192]
  float* rmF = (float*)(smem + 110592);        // [pi][wc][192]
  float* redW = (float*)(smem + 135168);       // [pi][8]
  float* red2 = (float*)(smem + 135424);       // [16]

  const int tid = threadIdx.x;
  const int lane = tid & 63;
  const int wid = tid >> 6;          // 0..7
  const int wr = wid >> 2;           // gal-row half (0/1): rows wr*96..+95
  const int wc = wid & 3;            // probe-col group: cols wc*48..+47
  const int q = lane >> 4;
  const int r16 = lane & 15;
  const int swz = (r16 & 7) << 4;

  const int g = blockIdx.x >> 3;
  const int pc = blockIdx.x & 7;     // 8 probes per block

  // persistent gallery A-frags: row = wr*96 + m*16 + r16
  const char* gbase = (const char*)(galT + (size_t)g * HW * NC);
  short8 a[6][4];
  #pragma unroll
  for (int m = 0; m < 6; ++m)
    #pragma unroll
    for (int ks = 0; ks < 4; ++ks)
      a[m][ks] = *(const short8*)(gbase + (wr * 96 + m * 16 + r16) * 256 + ks * 64 + q * 16);

  const char* pT = (const char*)probT + (size_t)(pc * 8) * PTB;

  // stage probe 0 into dbuf[0]: 48 chunks of 1KB, 6 per wave
  #pragma unroll
  for (int c = 0; c < 6; ++c)
    gl_lds16(pT + (wid * 6 + c) * 1024 + lane * 16,
             dbuf + (wid * 6 + c) * 1024);
  __syncthreads();

  const f32x4 zz = (f32x4){0.f, 0.f, 0.f, 0.f};

  for (int pi = 0; pi < 8; ++pi) {
    char* cur = dbuf + (pi & 1) * PTB;

    if (pi + 1 < 8) {   // async prefetch next probe into other buffer
      const char* src = pT + (size_t)(pi + 1) * PTB;
      char* dst = dbuf + ((pi + 1) & 1) * PTB;
      #pragma unroll
      for (int c = 0; c < 6; ++c)
        gl_lds16(src + (wid * 6 + c) * 1024 + lane * 16,
                 dst + (wid * 6 + c) * 1024);
    }

    __builtin_amdgcn_s_setprio(1);
    f32x4 acc[6][3];
    #pragma unroll
    for (int n = 0; n < 3; ++n) {
      const char* rowB = cur + (wc * 48 + n * 16 + r16) * 256;
      #pragma unroll
      for (int ks = 0; ks < 4; ++ks) {
        short8 bf = *(const short8*)(rowB + ((ks * 64 + q * 16) ^ swz));
        #pragma unroll
        for (int m = 0; m < 6; ++m)
          acc[m][n] = __builtin_amdgcn_mfma_f32_16x16x32_bf16(
              a[m][ks], bf, (ks == 0) ? zz : acc[m][n], 0, 0, 0);
      }
    }
    __builtin_amdgcn_s_setprio(0);

    // ---- col-max over this wave's 96 rows; cols = wc*48 + n*16 + r16 ----
    #pragma unroll
    for (int n = 0; n < 3; ++n) {
      float t8[8];
      #pragma unroll
      for (int k = 0; k < 8; ++k)
        t8[k] = max3f(acc[(3 * k) >> 2][n][(3 * k) & 3],
                      acc[(3 * k + 1) >> 2][n][(3 * k + 1) & 3],
                      acc[(3 * k + 2) >> 2][n][(3 * k + 2) & 3]);
      float u0 = max3f(t8[0], t8[1], t8[2]);
      float u1 = max3f(t8[3], t8[4], t8[5]);
      float cm = max3f(u0, u1, fmaxf(t8[6], t8[7]));
      cm = fmaxf(cm, __shfl_xor(cm, 16));
      cm = fmaxf(cm, __shfl_xor(cm, 32));
      if (lane < 16) cmP[pi * 384 + wr * 192 + wc * 48 + n * 16 + r16] = cm;
    }
    // ---- row-max over this wave's 48 cols; rows = wr*96 + m*16 + q*4 + j ----
    #pragma unroll
    for (int m = 0; m < 6; ++m)
      #pragma unroll
      for (int j = 0; j < 4; ++j) {
        float v = ror16_max(max3f(acc[m][0][j], acc[m][1][j], acc[m][2][j]));
        if (r16 == j) rmF[pi * 768 + wc * 192 + wr * 96 + m * 16 + q * 4 + j] = v;
      }
    __syncthreads();   // partials visible; prefetch drained; cur reads done
  }

  // ---- combine phase: all 8 probes ----
  const float w0 = (tid < 384) ? fc_w[tid] : 0.f;
  float s_acc = 0.f, q_acc = 0.f;
  #pragma unroll
  for (int pi = 0; pi < 8; ++pi) {
    float v = 0.f;
    if (tid < 192) {
      v = fmaxf(cmP[pi * 384 + tid], cmP[pi * 384 + 192 + tid]);
    } else if (tid < 384) {
      const float* r = rmF + pi * 768 + (tid - 192);
      v = fmaxf(max3f(r[0], r[192], r[384]), r[576]);
    }
    float wdot = v * w0;
    s_acc += v; q_acc += v * v;
    #pragma unroll
    for (int msk = 1; msk < 64; msk <<= 1) wdot += __shfl_xor(wdot, msk);
    if (lane == 0) redW[pi * 8 + wid] = wdot;
  }
  #pragma unroll
  for (int msk = 1; msk < 64; msk <<= 1) {
    s_acc += __shfl_xor(s_acc, msk);
    q_acc += __shfl_xor(q_acc, msk);
  }
  if (lane == 0) { red2[wid] = s_acc; red2[8 + wid] = q_acc; }
  __syncthreads();
  if (tid < 8) {
    const float* rw = redW + tid * 8;
    float s = rw[0] + rw[1] + rw[2] + rw[3] + rw[4] + rw[5] + rw[6] + rw[7];
    Wout[(pc * 8 + tid) * 64 + g] = s;
  }
  if (tid == 0) {
    sPart[blockIdx.x] = red2[0] + red2[1] + red2[2] + red2[3] +
                        red2[4] + red2[5] + red2[6] + red2[7];
    qPart[blockIdx.x] = red2[8] + red2[9] + red2[10] + red2[11] +
                        red2[12] + red2[13] + red2[14] + red2[15];
  }
}

// ---------------------------------------------------------------------------
// Finalize: exact BN -> fc -> BN chain. One block, 512 threads.
// ---------------------------------------------------------------------------
__device__ __forceinline__ float block_sum_512(float v, float* rbuf, float* bc) {
  int t = threadIdx.x, lane = t & 63, wid = t >> 6;
  #pragma unroll
  for (int m = 1; m < 64; m <<= 1) v += __shfl_xor(v, m);
  if (lane == 0) rbuf[wid] = v;
  __syncthreads();
  if (t == 0) {
    float r = 0.f;
    for (int i = 0; i < 8; ++i) r += rbuf[i];
    bc[0] = r;
  }
  __syncthreads();
  float res = bc[0];
  __syncthreads();
  return res;
}

__global__ __launch_bounds__(512)
void finalize_kernel(const float* __restrict__ Wv,
                     const float* __restrict__ sPart,
                     const float* __restrict__ qPart,
                     const float* __restrict__ fc_w,
                     const float* __restrict__ fc_b,
                     const float* __restrict__ bn_g,
                     const float* __restrict__ bn_b,
                     const float* __restrict__ lbn_g,
                     const float* __restrict__ lbn_b,
                     float* __restrict__ out) {
  __shared__ float rbuf[8];
  __shared__ float bc[1];
  const int t = threadIdx.x;  // 512

  float S = block_sum_512(sPart[t], rbuf, bc);
  float Q = block_sum_512(qPart[t], rbuf, bc);
  float SW = block_sum_512((t < 384) ? fc_w[t] : 0.f, rbuf, bc);

  const float Nf = 4096.0f * 384.0f;
  float mu = S / Nf;
  float var = Q / Nf - mu * mu;
  float istd = rsqrtf(var + KEPS);
  float cA = istd * bn_g[0];
  float off = bn_b[0] * SW + fc_b[0] - cA * mu * SW;

  float l[8];
  float ls = 0.f;
  #pragma unroll
  for (int i = 0; i < 8; ++i) {
    int n = t + i * 512;
    l[i] = cA * Wv[n] + off;
    ls += l[i];
  }
  float LS = block_sum_512(ls, rbuf, bc);
  float lmu = LS / 4096.0f;
  float lq = 0.f;
  #pragma unroll
  for (int i = 0; i < 8; ++i) { float d = l[i] - lmu; lq += d * d; }
  float LQ = block_sum_512(lq, rbuf, bc);
  float lvar = LQ / 4096.0f;
  float sc = lbn_g[0] * rsqrtf(lvar + KEPS);
  float lb = lbn_b[0];
  #pragma unroll
  for (int i = 0; i < 8; ++i) {
    int n = t + i * 512;
    out[n] = (l[i] - lmu) * sc + lb;
  }
}

// ---------------------------------------------------------------------------
extern "C" void kernel_launch(void* const* d_in, const int* in_sizes, int n_in,
                              void* d_out, int out_size, void* d_ws, size_t ws_size,
                              hipStream_t stream) {
  const float* prob  = (const float*)d_in[0];
  const float* gal   = (const float*)d_in[1];
  const float* bn_g  = (const float*)d_in[2];
  const float* bn_b  = (const float*)d_in[3];
  const float* fc_w  = (const float*)d_in[4];
  const float* fc_b  = (const float*)d_in[5];
  const float* lbn_g = (const float*)d_in[6];
  const float* lbn_b = (const float*)d_in[7];
  float* out = (float*)d_out;

  char* ws = (char*)d_ws;
  unsigned short* probT = (unsigned short*)(ws);            // 3,145,728 B
  unsigned short* galT  = (unsigned short*)(ws + 3145728);  // 3,145,728 B
  float* Wv    = (float*)(ws + 6291456);                    // 16384 B
  float* sPart = (float*)(ws + 6307840);                    // 2048 B
  float* qPart = (float*)(ws + 6309888);                    // 2048 B

  const int lds_bytes = 135488;
  hipFuncSetAttribute((const void*)pair_kernel,
                      hipFuncAttributeMaxDynamicSharedMemorySize, lds_bytes);

  prep_kernel<<<512, 256, 0, stream>>>(prob, gal, probT, galT);
  pair_kernel<<<512, 512, lds_bytes, stream>>>(galT, probT, fc_w, Wv, sPart, qPart);
  finalize_kernel<<<1, 512, 0, stream>>>(Wv, sPart, qPart, fc_w, fc_b,
                                         bn_g, bn_b, lbn_g, lbn_b, out);
}

// Round 8
// 63.863 us; speedup vs baseline: 1.3952x; 1.3952x over previous
//
#include <hip/hip_runtime.h>
#include <hip/hip_bf16.h>
#include <stdint.h>

#define HW 192
#define NC 128
#define KEPS 1e-5f
#define QTB 12288   /* 48-col quarter tile bytes */

typedef __attribute__((ext_vector_type(8))) short short8;
typedef __attribute__((ext_vector_type(4))) float f32x4;

__device__ __forceinline__ float max3f(float a, float b, float c) {
  float d;
  asm("v_max3_f32 %0, %1, %2, %3" : "=v"(d) : "v"(a), "v"(b), "v"(c));
  return d;
}

// ---------------------------------------------------------------------------
// Prep: f32 [n][C][HW] -> bf16 [n][HW][C] via LDS transpose (coalesced both
// sides). probT XOR-swizzled within each 256B row: byte col = (2c)^((hw&7)<<4).
// ---------------------------------------------------------------------------
__global__ __launch_bounds__(256)
void prep_kernel(const float* __restrict__ prob,
                 const float* __restrict__ gal,
                 unsigned short* __restrict__ probT,
                 unsigned short* __restrict__ galT) {
  __shared__ unsigned short lds[32 * 194];
  const int b = blockIdx.x;
  const int slice = b >> 2;
  const int cc = (b & 3) * 32;
  const bool isProbe = (slice < 64);
  const float* src = isProbe ? prob + (size_t)slice * NC * HW
                             : gal + (size_t)(slice - 64) * NC * HW;
  unsigned short* dst = isProbe ? probT + (size_t)slice * HW * NC
                                : galT + (size_t)(slice - 64) * HW * NC;
  const float* s0 = src + (size_t)cc * HW;
  #pragma unroll
  for (int k = 0; k < 24; ++k) {
    int i = k * 256 + threadIdx.x;
    int cp = i / HW;
    int hw = i - cp * HW;
    lds[cp * 194 + hw] =
        __builtin_bit_cast(unsigned short, __float2bfloat16(s0[i]));
  }
  __syncthreads();
  const int cp = threadIdx.x & 31;
  const int hw0 = threadIdx.x >> 5;
  const int c = cc + cp;
  #pragma unroll
  for (int k = 0; k < 24; ++k) {
    int hw = hw0 + 8 * k;
    unsigned short v = lds[cp * 194 + hw];
    int col = isProbe ? ((((2 * c) ^ ((hw & 7) << 4))) >> 1) : c;
    dst[hw * NC + col] = v;
  }
}

// ---------------------------------------------------------------------------
__device__ __forceinline__ void gl_lds16(const void* gsrc, void* ldst) {
  __builtin_amdgcn_global_load_lds(
      (const __attribute__((address_space(1))) void*)gsrc,
      (__attribute__((address_space(3))) void*)ldst, 16, 0, 0);
}

template <int CTRL>
__device__ __forceinline__ float dpp_max(float x) {
  int xi = __builtin_bit_cast(int, x);
  int yi = __builtin_amdgcn_update_dpp(xi, xi, CTRL, 0xf, 0xf, false);
  return fmaxf(x, __builtin_bit_cast(float, yi));
}
__device__ __forceinline__ float ror16_max(float x) {
  x = dpp_max<0x121>(x);
  x = dpp_max<0x122>(x);
  x = dpp_max<0x124>(x);
  x = dpp_max<0x128>(x);
  return x;
}

// ---------------------------------------------------------------------------
// Pair kernel: 1024 blocks = g*16 + pc (4 probes each); 4 waves of 48 gal
// rows each (A persistent in regs); step = 48-col quarter tile (12KB dbuf,
// async gl_lds). 32.3KB LDS + launch_bounds(256,4) -> 4 blocks/CU (16 w/CU).
// Per-probe combine with parity buffers; Wout flush deferred one step.
// ---------------------------------------------------------------------------
__global__ __launch_bounds__(256, 4)
void pair_kernel(const unsigned short* __restrict__ galT,
                 const unsigned short* __restrict__ probT,
                 const float* __restrict__ fc_w,
                 float* __restrict__ Wout,
                 float* __restrict__ sPart,
                 float* __restrict__ qPart) {
  __shared__ char ldsP[2][QTB];        // double-buffered quarter tile
  __shared__ float cmP[2][4][192];     // [probe parity][wid][col] col-max
  __shared__ float rmF[2][192];        // [probe parity][row] final row-max
  __shared__ float redp[2][4];         // [probe parity][wid] W partials
  __shared__ float red2[8];

  const int tid = threadIdx.x;
  const int lane = tid & 63;
  const int wid = tid >> 6;          // gal row group: rows wid*48..+47
  const int q = lane >> 4;
  const int r16 = lane & 15;
  const int swz = (r16 & 7) << 4;

  const int g = blockIdx.x >> 4;
  const int pc = blockIdx.x & 15;    // 4 probes per block

  // persistent gallery A-frags: row = wid*48 + m*16 + r16
  const char* gbase = (const char*)(galT + (size_t)g * HW * NC);
  short8 a[3][4];
  #pragma unroll
  for (int m = 0; m < 3; ++m)
    #pragma unroll
    for (int ks = 0; ks < 4; ++ks)
      a[m][ks] = *(const short8*)(gbase + (wid * 48 + m * 16 + r16) * 256 + ks * 64 + q * 16);

  const float w0 = fc_w[tid];                           // feat j = tid
  const float w1 = (tid < 128) ? fc_w[256 + tid] : 0.f; // feat j = 256+tid

  const char* pT = (const char*)probT + (size_t)(pc * 4) * 49152;

  // prologue: stage quarter 0
  #pragma unroll
  for (int ch = 0; ch < 3; ++ch)
    gl_lds16(pT + ch * 4096 + wid * 1024 + lane * 16,
             &ldsP[0][ch * 4096 + wid * 1024]);

  float rm[3][4];
  float s_acc = 0.f, q_acc = 0.f;
  const f32x4 zz = (f32x4){0.f, 0.f, 0.f, 0.f};

  for (int t = 0; t < 16; ++t) {
    const int qc = t & 3;            // quarter within probe
    const int pi = t >> 2;           // probe index within block
    const int par = pi & 1;
    __syncthreads();                 // prefetch(t) landed; partials visible

    if (t + 1 < 16) {                // async prefetch next quarter
      const char* src = pT + (size_t)(t + 1) * QTB;
      char* dst = ldsP[(t + 1) & 1];
      #pragma unroll
      for (int ch = 0; ch < 3; ++ch)
        gl_lds16(src + ch * 4096 + wid * 1024 + lane * 16,
                 dst + ch * 4096 + wid * 1024);
    }
    const char* cur = ldsP[t & 1];

    __builtin_amdgcn_s_setprio(1);
    f32x4 acc[3][3];
    #pragma unroll
    for (int n = 0; n < 3; ++n) {
      const char* rowB = cur + (n * 16 + r16) * 256;
      #pragma unroll
      for (int ks = 0; ks < 4; ++ks) {
        short8 bf = *(const short8*)(rowB + ((ks * 64 + q * 16) ^ swz));
        #pragma unroll
        for (int m = 0; m < 3; ++m)
          acc[m][n] = __builtin_amdgcn_mfma_f32_16x16x32_bf16(
              a[m][ks], bf, (ks == 0) ? zz : acc[m][n], 0, 0, 0);
      }
    }
    __builtin_amdgcn_s_setprio(0);

    // ---- combine for previous probe (qc==0, pi>=1): parity 1-par ----
    if (qc == 0 && t > 0) {
      const int pp = pi - 1;
      const int pa = pp & 1;
      float v;
      if (tid < 192) {
        float c01 = fmaxf(cmP[pa][0][tid], cmP[pa][1][tid]);
        v = max3f(c01, cmP[pa][2][tid], cmP[pa][3][tid]);
      } else {
        v = rmF[pa][tid - 192];        // rows 0..63 -> feat = tid
      }
      s_acc += v; q_acc += v * v;
      float w = v * w0;
      if (tid < 128) {
        float v1 = rmF[pa][tid + 64];  // rows 64..191 -> feat = 256+tid
        s_acc += v1; q_acc += v1 * v1;
        w += v1 * w1;
      }
      #pragma unroll
      for (int msk = 1; msk < 64; msk <<= 1) w += __shfl_xor(w, msk);
      if (lane == 0) redp[pa][wid] = w;
    }
    // ---- deferred Wout flush (qc==1, pi>=1): probe pi-1 ----
    if (qc == 1 && t > 1 && tid == 0) {
      const int pp = pi - 1;
      const int pa = pp & 1;
      Wout[(pc * 4 + pp) * 64 + g] =
          redp[pa][0] + redp[pa][1] + redp[pa][2] + redp[pa][3];
    }

    // ---- col-max over this wave's 48 rows (fold m,j in-lane; q via shfl) ----
    #pragma unroll
    for (int n = 0; n < 3; ++n) {
      float m0 = max3f(acc[0][n][0], acc[0][n][1], acc[0][n][2]);
      float m1 = max3f(acc[0][n][3], acc[1][n][0], acc[1][n][1]);
      float m2 = max3f(acc[1][n][2], acc[1][n][3], acc[2][n][0]);
      float m3 = max3f(acc[2][n][1], acc[2][n][2], acc[2][n][3]);
      float cm = max3f(m0, m1, m2);
      cm = fmaxf(cm, m3);
      cm = fmaxf(cm, __shfl_xor(cm, 16));
      cm = fmaxf(cm, __shfl_xor(cm, 32));
      if (lane < 16) cmP[par][wid][qc * 48 + n * 16 + r16] = cm;
    }
    // ---- row-max: fold over n in-lane, carry across quarters ----
    #pragma unroll
    for (int m = 0; m < 3; ++m)
      #pragma unroll
      for (int j = 0; j < 4; ++j) {
        float v = max3f(acc[m][0][j], acc[m][1][j], acc[m][2][j]);
        rm[m][j] = (qc == 0) ? v : fmaxf(rm[m][j], v);
      }
    if (qc == 3) {                   // finish: 16-lane DPP fold, publish
      #pragma unroll
      for (int m = 0; m < 3; ++m)
        #pragma unroll
        for (int j = 0; j < 4; ++j) {
          float v = ror16_max(rm[m][j]);
          if (r16 == j) rmF[par][wid * 48 + m * 16 + q * 4 + j] = v;
        }
    }
  }

  // ---- epilogue: combine + flush last probe (pi=3, parity 1) ----
  __syncthreads();
  {
    float v;
    if (tid < 192) {
      float c01 = fmaxf(cmP[1][0][tid], cmP[1][1][tid]);
      v = max3f(c01, cmP[1][2][tid], cmP[1][3][tid]);
    } else {
      v = rmF[1][tid - 192];
    }
    s_acc += v; q_acc += v * v;
    float w = v * w0;
    if (tid < 128) {
      float v1 = rmF[1][tid + 64];
      s_acc += v1; q_acc += v1 * v1;
      w += v1 * w1;
    }
    #pragma unroll
    for (int msk = 1; msk < 64; msk <<= 1) w += __shfl_xor(w, msk);
    if (lane == 0) redp[1][wid] = w;
  }
  #pragma unroll
  for (int msk = 1; msk < 64; msk <<= 1) {
    s_acc += __shfl_xor(s_acc, msk);
    q_acc += __shfl_xor(q_acc, msk);
  }
  if (lane == 0) { red2[wid] = s_acc; red2[4 + wid] = q_acc; }
  __syncthreads();
  if (tid == 0) {
    Wout[(pc * 4 + 3) * 64 + g] = redp[1][0] + redp[1][1] + redp[1][2] + redp[1][3];
    sPart[blockIdx.x] = red2[0] + red2[1] + red2[2] + red2[3];
    qPart[blockIdx.x] = red2[4] + red2[5] + red2[6] + red2[7];
  }
}

// ---------------------------------------------------------------------------
// Finalize: exact BN -> fc -> BN chain. One block, 1024 threads.
// ---------------------------------------------------------------------------
__device__ __forceinline__ float block_sum(float v, float* rbuf, float* bc, int nw) {
  int t = threadIdx.x, lane = t & 63, wid = t >> 6;
  #pragma unroll
  for (int m = 1; m < 64; m <<= 1) v += __shfl_xor(v, m);
  if (lane == 0) rbuf[wid] = v;
  __syncthreads();
  if (t == 0) {
    float r = 0.f;
    for (int i = 0; i < nw; ++i) r += rbuf[i];
    bc[0] = r;
  }
  __syncthreads();
  float res = bc[0];
  __syncthreads();
  return res;
}

__global__ __launch_bounds__(1024)
void finalize_kernel(const float* __restrict__ Wv,
                     const float* __restrict__ sPart,
                     const float* __restrict__ qPart,
                     const float* __restrict__ fc_w,
                     const float* __restrict__ fc_b,
                     const float* __restrict__ bn_g,
                     const float* __restrict__ bn_b,
                     const float* __restrict__ lbn_g,
                     const float* __restrict__ lbn_b,
                     float* __restrict__ out) {
  __shared__ float rbuf[16];
  __shared__ float bc[1];
  const int t = threadIdx.x;

  float S = block_sum(sPart[t], rbuf, bc, 16);
  float Q = block_sum(qPart[t], rbuf, bc, 16);
  float SW = block_sum((t < 384) ? fc_w[t] : 0.f, rbuf, bc, 16);

  const float Nf = 4096.0f * 384.0f;
  float mu = S / Nf;
  float var = Q / Nf - mu * mu;
  float istd = rsqrtf(var + KEPS);
  float cA = istd * bn_g[0];
  float off = bn_b[0] * SW + fc_b[0] - cA * mu * SW;

  float l[4];
  float ls = 0.f;
  #pragma unroll
  for (int i = 0; i < 4; ++i) {
    int n = t + i * 1024;
    l[i] = cA * Wv[n] + off;
    ls += l[i];
  }
  float LS = block_sum(ls, rbuf, bc, 16);
  float lmu = LS / 4096.0f;
  float lq = 0.f;
  #pragma unroll
  for (int i = 0; i < 4; ++i) { float d = l[i] - lmu; lq += d * d; }
  float LQ = block_sum(lq, rbuf, bc, 16);
  float lvar = LQ / 4096.0f;
  float sc = lbn_g[0] * rsqrtf(lvar + KEPS);
  float lb = lbn_b[0];
  #pragma unroll
  for (int i = 0; i < 4; ++i) {
    int n = t + i * 1024;
    out[n] = (l[i] - lmu) * sc + lb;
  }
}

// ---------------------------------------------------------------------------
extern "C" void kernel_launch(void* const* d_in, const int* in_sizes, int n_in,
                              void* d_out, int out_size, void* d_ws, size_t ws_size,
                              hipStream_t stream) {
  const float* prob  = (const float*)d_in[0];
  const float* gal   = (const float*)d_in[1];
  const float* bn_g  = (const float*)d_in[2];
  const float* bn_b  = (const float*)d_in[3];
  const float* fc_w  = (const float*)d_in[4];
  const float* fc_b  = (const float*)d_in[5];
  const float* lbn_g = (const float*)d_in[6];
  const float* lbn_b = (const float*)d_in[7];
  float* out = (float*)d_out;

  char* ws = (char*)d_ws;
  unsigned short* probT = (unsigned short*)(ws);            // 3,145,728 B
  unsigned short* galT  = (unsigned short*)(ws + 3145728);  // 3,145,728 B
  float* Wv    = (float*)(ws + 6291456);                    // 16384 B
  float* sPart = (float*)(ws + 6307840);                    // 4096 B
  float* qPart = (float*)(ws + 6311936);                    // 4096 B

  prep_kernel<<<512, 256, 0, stream>>>(prob, gal, probT, galT);
  pair_kernel<<<1024, 256, 0, stream>>>(galT, probT, fc_w, Wv, sPart, qPart);
  finalize_kernel<<<1, 1024, 0, stream>>>(Wv, sPart, qPart, fc_w, fc_b,
                                          bn_g, bn_b, lbn_g, lbn_b, out);
}

// Round 9
// 62.451 us; speedup vs baseline: 1.4267x; 1.0226x over previous
//
#include <hip/hip_runtime.h>
#include <hip/hip_bf16.h>
#include <stdint.h>

#define HW 192
#define NC 128
#define KEPS 1e-5f
#define QTB 12288   /* 48-col quarter tile bytes */

typedef __attribute__((ext_vector_type(8))) short short8;
typedef __attribute__((ext_vector_type(4))) float f32x4;

__device__ __forceinline__ float max3f(float a, float b, float c) {
  float d;
  asm("v_max3_f32 %0, %1, %2, %3" : "=v"(d) : "v"(a), "v"(b), "v"(c));
  return d;
}

// ---------------------------------------------------------------------------
// Prep: f32 [n][C][HW] -> bf16 [n][HW][C] via LDS transpose (coalesced both
// sides). probT XOR-swizzled within each 256B row: byte col = (2c)^((hw&7)<<4).
// ---------------------------------------------------------------------------
__global__ __launch_bounds__(256)
void prep_kernel(const float* __restrict__ prob,
                 const float* __restrict__ gal,
                 unsigned short* __restrict__ probT,
                 unsigned short* __restrict__ galT) {
  __shared__ unsigned short lds[32 * 194];
  const int b = blockIdx.x;
  const int slice = b >> 2;
  const int cc = (b & 3) * 32;
  const bool isProbe = (slice < 64);
  const float* src = isProbe ? prob + (size_t)slice * NC * HW
                             : gal + (size_t)(slice - 64) * NC * HW;
  unsigned short* dst = isProbe ? probT + (size_t)slice * HW * NC
                                : galT + (size_t)(slice - 64) * HW * NC;
  const float* s0 = src + (size_t)cc * HW;
  #pragma unroll
  for (int k = 0; k < 24; ++k) {
    int i = k * 256 + threadIdx.x;
    int cp = i / HW;
    int hw = i - cp * HW;
    lds[cp * 194 + hw] =
        __builtin_bit_cast(unsigned short, __float2bfloat16(s0[i]));
  }
  __syncthreads();
  const int cp = threadIdx.x & 31;
  const int hw0 = threadIdx.x >> 5;
  const int c = cc + cp;
  #pragma unroll
  for (int k = 0; k < 24; ++k) {
    int hw = hw0 + 8 * k;
    unsigned short v = lds[cp * 194 + hw];
    int col = isProbe ? ((((2 * c) ^ ((hw & 7) << 4))) >> 1) : c;
    dst[hw * NC + col] = v;
  }
}

// ---------------------------------------------------------------------------
__device__ __forceinline__ void gl_lds16(const void* gsrc, void* ldst) {
  __builtin_amdgcn_global_load_lds(
      (const __attribute__((address_space(1))) void*)gsrc,
      (__attribute__((address_space(3))) void*)ldst, 16, 0, 0);
}

template <int CTRL>
__device__ __forceinline__ float dpp_max(float x) {
  int xi = __builtin_bit_cast(int, x);
  int yi = __builtin_amdgcn_update_dpp(xi, xi, CTRL, 0xf, 0xf, false);
  return fmaxf(x, __builtin_bit_cast(float, yi));
}
__device__ __forceinline__ float ror16_max(float x) {
  x = dpp_max<0x121>(x);
  x = dpp_max<0x122>(x);
  x = dpp_max<0x124>(x);
  x = dpp_max<0x128>(x);
  return x;
}

// ---------------------------------------------------------------------------
// Pair kernel (R8 structure + counted-vmcnt light barriers, T3/T4):
// 1024 blocks = g*16 + pc (4 probes each); 4 waves of 48 gal rows (A in regs);
// step = 48-col quarter tile (12KB dbuf, async gl_lds). Per step:
//   issue prefetch(t+1) -> vmcnt(3) -> s_barrier -> compute ->
//   lgkmcnt(0) -> s_barrier.   NEVER vmcnt(0) in the main loop.
// ---------------------------------------------------------------------------
__global__ __launch_bounds__(256, 4)
void pair_kernel(const unsigned short* __restrict__ galT,
                 const unsigned short* __restrict__ probT,
                 const float* __restrict__ fc_w,
                 float* __restrict__ Wout,
                 float* __restrict__ sPart,
                 float* __restrict__ qPart) {
  __shared__ char ldsP[2][QTB];        // double-buffered quarter tile
  __shared__ float cmP[2][4][192];     // [probe parity][wid][col] col-max
  __shared__ float rmF[2][192];        // [probe parity][row] final row-max
  __shared__ float redp[2][4];         // [probe parity][wid] W partials
  __shared__ float red2[8];

  const int tid = threadIdx.x;
  const int lane = tid & 63;
  const int wid = tid >> 6;          // gal row group: rows wid*48..+47
  const int q = lane >> 4;
  const int r16 = lane & 15;
  const int swz = (r16 & 7) << 4;

  const int g = blockIdx.x >> 4;
  const int pc = blockIdx.x & 15;    // 4 probes per block

  // persistent gallery A-frags: row = wid*48 + m*16 + r16
  const char* gbase = (const char*)(galT + (size_t)g * HW * NC);
  short8 a[3][4];
  #pragma unroll
  for (int m = 0; m < 3; ++m)
    #pragma unroll
    for (int ks = 0; ks < 4; ++ks)
      a[m][ks] = *(const short8*)(gbase + (wid * 48 + m * 16 + r16) * 256 + ks * 64 + q * 16);

  const float w0 = fc_w[tid];                           // feat j = tid
  const float w1 = (tid < 128) ? fc_w[256 + tid] : 0.f; // feat j = 256+tid

  const char* pT = (const char*)probT + (size_t)(pc * 4) * 49152;

  // prologue: stage quarter 0 (3 gl_lds per wave)
  #pragma unroll
  for (int ch = 0; ch < 3; ++ch)
    gl_lds16(pT + ch * 4096 + wid * 1024 + lane * 16,
             &ldsP[0][ch * 4096 + wid * 1024]);

  float rm[3][4];
  float s_acc = 0.f, q_acc = 0.f;
  const f32x4 zz = (f32x4){0.f, 0.f, 0.f, 0.f};

  for (int t = 0; t < 16; ++t) {
    const int qc = t & 3;            // quarter within probe
    const int pi = t >> 2;           // probe index within block
    const int par = pi & 1;

    // ---- issue prefetch(t+1), then wait ONLY tile-t's loads (counted) ----
    if (t + 1 < 16) {
      const char* src = pT + (size_t)(t + 1) * QTB;
      char* dst = ldsP[(t + 1) & 1];
      #pragma unroll
      for (int ch = 0; ch < 3; ++ch)
        gl_lds16(src + ch * 4096 + wid * 1024 + lane * 16,
                 dst + ch * 4096 + wid * 1024);
      asm volatile("s_waitcnt vmcnt(3)" ::: "memory");
    } else {
      asm volatile("s_waitcnt vmcnt(0)" ::: "memory");
    }
    __builtin_amdgcn_sched_barrier(0);
    __builtin_amdgcn_s_barrier();    // all waves' tile-t chunks landed
    const char* cur = ldsP[t & 1];

    // ---- combine for previous probe (qc==0, pi>=1): parity 1-par ----
    if (qc == 0 && t > 0) {
      const int pp = pi - 1;
      const int pa = pp & 1;
      float v;
      if (tid < 192) {
        float c01 = fmaxf(cmP[pa][0][tid], cmP[pa][1][tid]);
        v = max3f(c01, cmP[pa][2][tid], cmP[pa][3][tid]);
      } else {
        v = rmF[pa][tid - 192];        // rows 0..63 -> feat = tid
      }
      s_acc += v; q_acc += v * v;
      float w = v * w0;
      if (tid < 128) {
        float v1 = rmF[pa][tid + 64];  // rows 64..191 -> feat = 256+tid
        s_acc += v1; q_acc += v1 * v1;
        w += v1 * w1;
      }
      #pragma unroll
      for (int msk = 1; msk < 64; msk <<= 1) w += __shfl_xor(w, msk);
      if (lane == 0) redp[pa][wid] = w;
    }
    // ---- deferred Wout flush (qc==1, pi>=1): probe pi-1 ----
    if (qc == 1 && t > 1 && tid == 0) {
      const int pp = pi - 1;
      const int pa = pp & 1;
      Wout[(pc * 4 + pp) * 64 + g] =
          redp[pa][0] + redp[pa][1] + redp[pa][2] + redp[pa][3];
    }

    __builtin_amdgcn_s_setprio(1);
    f32x4 acc[3][3];
    #pragma unroll
    for (int n = 0; n < 3; ++n) {
      const char* rowB = cur + (n * 16 + r16) * 256;
      #pragma unroll
      for (int ks = 0; ks < 4; ++ks) {
        short8 bf = *(const short8*)(rowB + ((ks * 64 + q * 16) ^ swz));
        #pragma unroll
        for (int m = 0; m < 3; ++m)
          acc[m][n] = __builtin_amdgcn_mfma_f32_16x16x32_bf16(
              a[m][ks], bf, (ks == 0) ? zz : acc[m][n], 0, 0, 0);
      }
    }
    __builtin_amdgcn_s_setprio(0);

    // ---- col-max over this wave's 48 rows (fold m,j in-lane; q via shfl) ----
    #pragma unroll
    for (int n = 0; n < 3; ++n) {
      float m0 = max3f(acc[0][n][0], acc[0][n][1], acc[0][n][2]);
      float m1 = max3f(acc[0][n][3], acc[1][n][0], acc[1][n][1]);
      float m2 = max3f(acc[1][n][2], acc[1][n][3], acc[2][n][0]);
      float m3 = max3f(acc[2][n][1], acc[2][n][2], acc[2][n][3]);
      float cm = max3f(m0, m1, m2);
      cm = fmaxf(cm, m3);
      cm = fmaxf(cm, __shfl_xor(cm, 16));
      cm = fmaxf(cm, __shfl_xor(cm, 32));
      if (lane < 16) cmP[par][wid][qc * 48 + n * 16 + r16] = cm;
    }
    // ---- row-max: fold over n in-lane, carry across quarters ----
    #pragma unroll
    for (int m = 0; m < 3; ++m)
      #pragma unroll
      for (int j = 0; j < 4; ++j) {
        float v = max3f(acc[m][0][j], acc[m][1][j], acc[m][2][j]);
        rm[m][j] = (qc == 0) ? v : fmaxf(rm[m][j], v);
      }
    if (qc == 3) {                   // finish: 16-lane DPP fold, publish
      #pragma unroll
      for (int m = 0; m < 3; ++m)
        #pragma unroll
        for (int j = 0; j < 4; ++j) {
          float v = ror16_max(rm[m][j]);
          if (r16 == j) rmF[par][wid * 48 + m * 16 + q * 4 + j] = v;
        }
    }

    // ---- end-of-step: own LDS ops drained, then light barrier ----
    asm volatile("s_waitcnt lgkmcnt(0)" ::: "memory");
    __builtin_amdgcn_sched_barrier(0);
    __builtin_amdgcn_s_barrier();    // writes visible; buf reads done
  }

  // ---- epilogue: combine + flush last probe (pi=3, parity 1) ----
  {
    float v;
    if (tid < 192) {
      float c01 = fmaxf(cmP[1][0][tid], cmP[1][1][tid]);
      v = max3f(c01, cmP[1][2][tid], cmP[1][3][tid]);
    } else {
      v = rmF[1][tid - 192];
    }
    s_acc += v; q_acc += v * v;
    float w = v * w0;
    if (tid < 128) {
      float v1 = rmF[1][tid + 64];
      s_acc += v1; q_acc += v1 * v1;
      w += v1 * w1;
    }
    #pragma unroll
    for (int msk = 1; msk < 64; msk <<= 1) w += __shfl_xor(w, msk);
    if (lane == 0) redp[1][wid] = w;
  }
  #pragma unroll
  for (int msk = 1; msk < 64; msk <<= 1) {
    s_acc += __shfl_xor(s_acc, msk);
    q_acc += __shfl_xor(q_acc, msk);
  }
  if (lane == 0) { red2[wid] = s_acc; red2[4 + wid] = q_acc; }
  __syncthreads();
  if (tid == 0) {
    Wout[(pc * 4 + 3) * 64 + g] = redp[1][0] + redp[1][1] + redp[1][2] + redp[1][3];
    sPart[blockIdx.x] = red2[0] + red2[1] + red2[2] + red2[3];
    qPart[blockIdx.x] = red2[4] + red2[5] + red2[6] + red2[7];
  }
}

// ---------------------------------------------------------------------------
// Finalize: exact BN -> fc -> BN chain. One block, 1024 threads.
// ---------------------------------------------------------------------------
__device__ __forceinline__ float block_sum(float v, float* rbuf, float* bc, int nw) {
  int t = threadIdx.x, lane = t & 63, wid = t >> 6;
  #pragma unroll
  for (int m = 1; m < 64; m <<= 1) v += __shfl_xor(v, m);
  if (lane == 0) rbuf[wid] = v;
  __syncthreads();
  if (t == 0) {
    float r = 0.f;
    for (int i = 0; i < nw; ++i) r += rbuf[i];
    bc[0] = r;
  }
  __syncthreads();
  float res = bc[0];
  __syncthreads();
  return res;
}

__global__ __launch_bounds__(1024)
void finalize_kernel(const float* __restrict__ Wv,
                     const float* __restrict__ sPart,
                     const float* __restrict__ qPart,
                     const float* __restrict__ fc_w,
                     const float* __restrict__ fc_b,
                     const float* __restrict__ bn_g,
                     const float* __restrict__ bn_b,
                     const float* __restrict__ lbn_g,
                     const float* __restrict__ lbn_b,
                     float* __restrict__ out) {
  __shared__ float rbuf[16];
  __shared__ float bc[1];
  const int t = threadIdx.x;

  float S = block_sum(sPart[t], rbuf, bc, 16);
  float Q = block_sum(qPart[t], rbuf, bc, 16);
  float SW = block_sum((t < 384) ? fc_w[t] : 0.f, rbuf, bc, 16);

  const float Nf = 4096.0f * 384.0f;
  float mu = S / Nf;
  float var = Q / Nf - mu * mu;
  float istd = rsqrtf(var + KEPS);
  float cA = istd * bn_g[0];
  float off = bn_b[0] * SW + fc_b[0] - cA * mu * SW;

  float l[4];
  float ls = 0.f;
  #pragma unroll
  for (int i = 0; i < 4; ++i) {
    int n = t + i * 1024;
    l[i] = cA * Wv[n] + off;
    ls += l[i];
  }
  float LS = block_sum(ls, rbuf, bc, 16);
  float lmu = LS / 4096.0f;
  float lq = 0.f;
  #pragma unroll
  for (int i = 0; i < 4; ++i) { float d = l[i] - lmu; lq += d * d; }
  float LQ = block_sum(lq, rbuf, bc, 16);
  float lvar = LQ / 4096.0f;
  float sc = lbn_g[0] * rsqrtf(lvar + KEPS);
  float lb = lbn_b[0];
  #pragma unroll
  for (int i = 0; i < 4; ++i) {
    int n = t + i * 1024;
    out[n] = (l[i] - lmu) * sc + lb;
  }
}

// ---------------------------------------------------------------------------
extern "C" void kernel_launch(void* const* d_in, const int* in_sizes, int n_in,
                              void* d_out, int out_size, void* d_ws, size_t ws_size,
                              hipStream_t stream) {
  const float* prob  = (const float*)d_in[0];
  const float* gal   = (const float*)d_in[1];
  const float* bn_g  = (const float*)d_in[2];
  const float* bn_b  = (const float*)d_in[3];
  const float* fc_w  = (const float*)d_in[4];
  const float* fc_b  = (const float*)d_in[5];
  const float* lbn_g = (const float*)d_in[6];
  const float* lbn_b = (const float*)d_in[7];
  float* out = (float*)d_out;

  char* ws = (char*)d_ws;
  unsigned short* probT = (unsigned short*)(ws);            // 3,145,728 B
  unsigned short* galT  = (unsigned short*)(ws + 3145728);  // 3,145,728 B
  float* Wv    = (float*)(ws + 6291456);                    // 16384 B
  float* sPart = (float*)(ws + 6307840);                    // 4096 B
  float* qPart = (float*)(ws + 6311936);                    // 4096 B

  prep_kernel<<<512, 256, 0, stream>>>(prob, gal, probT, galT);
  pair_kernel<<<1024, 256, 0, stream>>>(galT, probT, fc_w, Wv, sPart, qPart);
  finalize_kernel<<<1, 1024, 0, stream>>>(Wv, sPart, qPart, fc_w, fc_b,
                                          bn_g, bn_b, lbn_g, lbn_b, out);
}

// Round 10
// 59.218 us; speedup vs baseline: 1.5046x; 1.0546x over previous
//
#include <hip/hip_runtime.h>
#include <hip/hip_bf16.h>
#include <stdint.h>

#define HW 192
#define NC 128
#define KEPS 1e-5f
#define SLICE_B 49152   /* bytes per image in frag layout */

typedef __attribute__((ext_vector_type(8))) short short8;
typedef __attribute__((ext_vector_type(4))) float f32x4;

__device__ __forceinline__ float max3f(float a, float b, float c) {
  float d;
  asm("v_max3_f32 %0, %1, %2, %3" : "=v"(d) : "v"(a), "v"(b), "v"(c));
  return d;
}

// ---------------------------------------------------------------------------
// Prep: f32 [n][C][HW] -> MFMA-fragment layout, both tensors:
//   chunk(tile 0..11, ks 0..3, lane 0..63) of 16B at
//   base + ((tile*4+ks)*64+lane)*16, holding 8 bf16:
//   value[j] = img[c = ks*32 + (lane>>4)*8 + j][s = tile*16 + (lane&15)]
// This is exactly the 16x16x32 A/B fragment each lane needs -> pair kernel
// loads are single coalesced dwordx4 (lane*16 contiguous).
// 512 blocks = 128 slices x 4 ks-chunks of 32 channels.
// ---------------------------------------------------------------------------
__global__ __launch_bounds__(256)
void prep_kernel(const float* __restrict__ prob,
                 const float* __restrict__ gal,
                 char* __restrict__ probF,
                 char* __restrict__ galF) {
  __shared__ unsigned short lds[32 * 194];
  const int b = blockIdx.x;
  const int slice = b >> 2;
  const int ks = b & 3;
  const bool isProbe = (slice < 64);
  const float* src = isProbe ? prob + (size_t)slice * NC * HW
                             : gal + (size_t)(slice - 64) * NC * HW;
  char* dstBase = isProbe ? probF + (size_t)slice * SLICE_B
                          : galF + (size_t)(slice - 64) * SLICE_B;
  // read phase: 32 channels x 192 positions, contiguous f32
  const float* s0 = src + (size_t)(ks * 32) * HW;
  #pragma unroll
  for (int k = 0; k < 24; ++k) {
    int i = k * 256 + threadIdx.x;
    int cp = i / HW;
    int hw = i - cp * HW;
    lds[cp * 194 + hw] =
        __builtin_bit_cast(unsigned short, __float2bfloat16(s0[i]));
  }
  __syncthreads();
  // write phase: 768 fragment-slots, 3 per thread
  #pragma unroll
  for (int rep = 0; rep < 3; ++rep) {
    int idx = rep * 256 + threadIdx.x;   // 0..767
    int tile = idx >> 6;                 // 0..11
    int lane = idx & 63;
    int q = lane >> 4;
    int r16 = lane & 15;
    int s = tile * 16 + r16;
    unsigned short v[8];
    #pragma unroll
    for (int j = 0; j < 8; ++j) v[j] = lds[(q * 8 + j) * 194 + s];
    short8 pack;
    #pragma unroll
    for (int j = 0; j < 8; ++j) pack[j] = (short)v[j];
    *(short8*)(dstBase + (((tile * 4 + ks) * 64 + lane) * 16)) = pack;
  }
}

template <int CTRL>
__device__ __forceinline__ float dpp_max(float x) {
  int xi = __builtin_bit_cast(int, x);
  int yi = __builtin_amdgcn_update_dpp(xi, xi, CTRL, 0xf, 0xf, false);
  return fmaxf(x, __builtin_bit_cast(float, yi));
}
__device__ __forceinline__ float ror16_max(float x) {
  x = dpp_max<0x121>(x);
  x = dpp_max<0x122>(x);
  x = dpp_max<0x124>(x);
  x = dpp_max<0x128>(x);
  return x;
}

// ---------------------------------------------------------------------------
// Pair kernel, barrier-free streaming: 2048 blocks = g*32 + pc (2 probes).
// XCD = pc%8 -> each XCD owns 8 probes (384KB) + all galleries (3MB) in L2.
// 4 waves = 4 gallery row-groups of 48 (A frags persistent, 48 VGPR).
// B frags load straight from cache (coalesced dwordx4) -- no LDS staging,
// no barriers in the main loop; L1 broadcasts the x4 within-block reuse.
// Only 2 __syncthreads per block (combine phase).
// ---------------------------------------------------------------------------
__global__ __launch_bounds__(256, 3)
void pair_kernel(const char* __restrict__ galF,
                 const char* __restrict__ probF,
                 const float* __restrict__ fc_w,
                 float* __restrict__ Wout,
                 float* __restrict__ sPart,
                 float* __restrict__ qPart) {
  __shared__ float cmP[2][4][192];   // [probe][wid][col] col-max partials
  __shared__ float rmF[2][192];      // [probe][row] final row-max
  __shared__ float red[2][4];        // [probe][wid] W partials
  __shared__ float red2[8];

  const int tid = threadIdx.x;
  const int lane = tid & 63;
  const int wid = tid >> 6;          // gallery row group: rows wid*48..+47
  const int q = lane >> 4;
  const int r16 = lane & 15;

  const int g = blockIdx.x >> 5;
  const int pc = blockIdx.x & 31;    // probes 2pc, 2pc+1

  // persistent gallery A-frags (coalesced frag loads)
  const char* gB = galF + (size_t)g * SLICE_B + lane * 16;
  short8 a[3][4];
  #pragma unroll
  for (int m = 0; m < 3; ++m)
    #pragma unroll
    for (int ks = 0; ks < 4; ++ks)
      a[m][ks] = *(const short8*)(gB + (((wid * 3 + m) * 4 + ks) * 1024));

  const float w0 = fc_w[tid];                           // feat j = tid
  const float w1 = (tid < 128) ? fc_w[256 + tid] : 0.f; // feat j = 256+tid

  float s_acc = 0.f, q_acc = 0.f;
  const f32x4 zz = (f32x4){0.f, 0.f, 0.f, 0.f};

  #pragma unroll 1
  for (int pi = 0; pi < 2; ++pi) {
    const char* pB = probF + (size_t)(pc * 2 + pi) * SLICE_B + lane * 16;
    float rm[3][4];

    #pragma unroll 1
    for (int qt = 0; qt < 4; ++qt) {
      f32x4 acc[3][3];
      __builtin_amdgcn_s_setprio(1);
      #pragma unroll
      for (int nt = 0; nt < 3; ++nt) {
        const char* bb = pB + ((qt * 3 + nt) * 4) * 1024;
        short8 b0 = *(const short8*)(bb);
        short8 b1 = *(const short8*)(bb + 1024);
        short8 b2 = *(const short8*)(bb + 2048);
        short8 b3 = *(const short8*)(bb + 3072);
        #pragma unroll
        for (int m = 0; m < 3; ++m)
          acc[m][nt] = __builtin_amdgcn_mfma_f32_16x16x32_bf16(a[m][0], b0, zz, 0, 0, 0);
        #pragma unroll
        for (int m = 0; m < 3; ++m)
          acc[m][nt] = __builtin_amdgcn_mfma_f32_16x16x32_bf16(a[m][1], b1, acc[m][nt], 0, 0, 0);
        #pragma unroll
        for (int m = 0; m < 3; ++m)
          acc[m][nt] = __builtin_amdgcn_mfma_f32_16x16x32_bf16(a[m][2], b2, acc[m][nt], 0, 0, 0);
        #pragma unroll
        for (int m = 0; m < 3; ++m)
          acc[m][nt] = __builtin_amdgcn_mfma_f32_16x16x32_bf16(a[m][3], b3, acc[m][nt], 0, 0, 0);
      }
      __builtin_amdgcn_s_setprio(0);

      // col-max over this wave's 48 rows; cols = qt*48 + nt*16 + r16
      #pragma unroll
      for (int nt = 0; nt < 3; ++nt) {
        float m0 = max3f(acc[0][nt][0], acc[0][nt][1], acc[0][nt][2]);
        float m1 = max3f(acc[0][nt][3], acc[1][nt][0], acc[1][nt][1]);
        float m2 = max3f(acc[1][nt][2], acc[1][nt][3], acc[2][nt][0]);
        float m3 = max3f(acc[2][nt][1], acc[2][nt][2], acc[2][nt][3]);
        float cm = max3f(m0, m1, m2);
        cm = fmaxf(cm, m3);
        cm = fmaxf(cm, __shfl_xor(cm, 16));
        cm = fmaxf(cm, __shfl_xor(cm, 32));
        if (lane < 16) cmP[pi][wid][qt * 48 + nt * 16 + r16] = cm;
      }
      // row-max: fold over nt in-lane, carry across quarters
      #pragma unroll
      for (int m = 0; m < 3; ++m)
        #pragma unroll
        for (int j = 0; j < 4; ++j) {
          float v = max3f(acc[m][0][j], acc[m][1][j], acc[m][2][j]);
          rm[m][j] = (qt == 0) ? v : fmaxf(rm[m][j], v);
        }
    }
    // finish row-max: 16-lane DPP fold, publish rows wid*48 + m*16 + q*4 + j
    #pragma unroll
    for (int m = 0; m < 3; ++m)
      #pragma unroll
      for (int j = 0; j < 4; ++j) {
        float v = ror16_max(rm[m][j]);
        if (r16 == j) rmF[pi][wid * 48 + m * 16 + q * 4 + j] = v;
      }
  }

  __syncthreads();   // all partials visible

  // ---- combine: both probes ----
  #pragma unroll
  for (int pi = 0; pi < 2; ++pi) {
    float v;
    if (tid < 192) {
      float c01 = fmaxf(cmP[pi][0][tid], cmP[pi][1][tid]);
      v = max3f(c01, cmP[pi][2][tid], cmP[pi][3][tid]);
    } else {
      v = rmF[pi][tid - 192];          // rows 0..63 -> feat j = tid
    }
    s_acc += v; q_acc += v * v;
    float w = v * w0;
    if (tid < 128) {
      float v1 = rmF[pi][tid + 64];    // rows 64..191 -> feat j = 256+tid
      s_acc += v1; q_acc += v1 * v1;
      w += v1 * w1;
    }
    #pragma unroll
    for (int msk = 1; msk < 64; msk <<= 1) w += __shfl_xor(w, msk);
    if (lane == 0) red[pi][wid] = w;
  }
  #pragma unroll
  for (int msk = 1; msk < 64; msk <<= 1) {
    s_acc += __shfl_xor(s_acc, msk);
    q_acc += __shfl_xor(q_acc, msk);
  }
  if (lane == 0) { red2[wid] = s_acc; red2[4 + wid] = q_acc; }
  __syncthreads();
  if (tid < 2)
    Wout[(pc * 2 + tid) * 64 + g] =
        red[tid][0] + red[tid][1] + red[tid][2] + red[tid][3];
  if (tid == 0) {
    sPart[blockIdx.x] = red2[0] + red2[1] + red2[2] + red2[3];
    qPart[blockIdx.x] = red2[4] + red2[5] + red2[6] + red2[7];
  }
}

// ---------------------------------------------------------------------------
// Finalize: exact BN -> fc -> BN chain. One block, 1024 threads.
// sPart/qPart now have 2048 entries.
// ---------------------------------------------------------------------------
__device__ __forceinline__ float block_sum(float v, float* rbuf, float* bc, int nw) {
  int t = threadIdx.x, lane = t & 63, wid = t >> 6;
  #pragma unroll
  for (int m = 1; m < 64; m <<= 1) v += __shfl_xor(v, m);
  if (lane == 0) rbuf[wid] = v;
  __syncthreads();
  if (t == 0) {
    float r = 0.f;
    for (int i = 0; i < nw; ++i) r += rbuf[i];
    bc[0] = r;
  }
  __syncthreads();
  float res = bc[0];
  __syncthreads();
  return res;
}

__global__ __launch_bounds__(1024)
void finalize_kernel(const float* __restrict__ Wv,
                     const float* __restrict__ sPart,
                     const float* __restrict__ qPart,
                     const float* __restrict__ fc_w,
                     const float* __restrict__ fc_b,
                     const float* __restrict__ bn_g,
                     const float* __restrict__ bn_b,
                     const float* __restrict__ lbn_g,
                     const float* __restrict__ lbn_b,
                     float* __restrict__ out) {
  __shared__ float rbuf[16];
  __shared__ float bc[1];
  const int t = threadIdx.x;

  float S = block_sum(sPart[t] + sPart[t + 1024], rbuf, bc, 16);
  float Q = block_sum(qPart[t] + qPart[t + 1024], rbuf, bc, 16);
  float SW = block_sum((t < 384) ? fc_w[t] : 0.f, rbuf, bc, 16);

  const float Nf = 4096.0f * 384.0f;
  float mu = S / Nf;
  float var = Q / Nf - mu * mu;
  float istd = rsqrtf(var + KEPS);
  float cA = istd * bn_g[0];
  float off = bn_b[0] * SW + fc_b[0] - cA * mu * SW;

  float l[4];
  float ls = 0.f;
  #pragma unroll
  for (int i = 0; i < 4; ++i) {
    int n = t + i * 1024;
    l[i] = cA * Wv[n] + off;
    ls += l[i];
  }
  float LS = block_sum(ls, rbuf, bc, 16);
  float lmu = LS / 4096.0f;
  float lq = 0.f;
  #pragma unroll
  for (int i = 0; i < 4; ++i) { float d = l[i] - lmu; lq += d * d; }
  float LQ = block_sum(lq, rbuf, bc, 16);
  float lvar = LQ / 4096.0f;
  float sc = lbn_g[0] * rsqrtf(lvar + KEPS);
  float lb = lbn_b[0];
  #pragma unroll
  for (int i = 0; i < 4; ++i) {
    int n = t + i * 1024;
    out[n] = (l[i] - lmu) * sc + lb;
  }
}

// ---------------------------------------------------------------------------
extern "C" void kernel_launch(void* const* d_in, const int* in_sizes, int n_in,
                              void* d_out, int out_size, void* d_ws, size_t ws_size,
                              hipStream_t stream) {
  const float* prob  = (const float*)d_in[0];
  const float* gal   = (const float*)d_in[1];
  const float* bn_g  = (const float*)d_in[2];
  const float* bn_b  = (const float*)d_in[3];
  const float* fc_w  = (const float*)d_in[4];
  const float* fc_b  = (const float*)d_in[5];
  const float* lbn_g = (const float*)d_in[6];
  const float* lbn_b = (const float*)d_in[7];
  float* out = (float*)d_out;

  char* ws = (char*)d_ws;
  char* probF = ws;                                  // 3,145,728 B
  char* galF  = ws + 3145728;                        // 3,145,728 B
  float* Wv    = (float*)(ws + 6291456);             // 16384 B
  float* sPart = (float*)(ws + 6307840);             // 8192 B
  float* qPart = (float*)(ws + 6316032);             // 8192 B

  prep_kernel<<<512, 256, 0, stream>>>(prob, gal, probF, galF);
  pair_kernel<<<2048, 256, 0, stream>>>(galF, probF, fc_w, Wv, sPart, qPart);
  finalize_kernel<<<1, 1024, 0, stream>>>(Wv, sPart, qPart, fc_w, fc_b,
                                          bn_g, bn_b, lbn_g, lbn_b, out);
}